// Round 18
// baseline (484.224 us; speedup 1.0000x reference)
//
#include <hip/hip_runtime.h>

#define N_NODES 100000
#define N_EDGES 1600000
#define T_STEPS 6
#define FDIM    64
#define SEG     (T_STEPS * N_NODES)
#define C2      0.01f
#define PADF    68   // LDS row stride: 17 quads, 16B-aligned float4 rows
#define RFL __builtin_amdgcn_readfirstlane

// Build per-(t,dst)-segment linked lists over edges. One atomicExch per edge
// on the 2.4MB head array (L2-resident).
__global__ __launch_bounds__(256) void k_build(
    const int* __restrict__ dst, const int* __restrict__ tix,
    int* __restrict__ head, int* __restrict__ nxt)
{
  const int e = blockIdx.x * blockDim.x + threadIdx.x;
  if (e >= N_EDGES) return;
  const int key = tix[e] * N_NODES + dst[e];
  nxt[e] = atomicExch(&head[key], e);
}

// r17 scalarized-branchless walker, extended to 2 NODES per wave = 12
// concurrent chains. r17 post-mortem: VALU fixed (70->40%) but time ~flat ->
// gather-concurrency-bound (~138 chains/CU). Doubling chains/wave doubles
// MLP at the same wave count budget. r11's 24-chain failure is avoided:
// chain state in SGPRs (r17: VGPR 24; here ~40, still 8 waves/SIMD),
// branchless clamped loads (r13), and only 12 chains (straggler cost ~+0.5
// iter). Per-segment visit order and adds unchanged -> bit-identical output.
__global__ __launch_bounds__(256) void k_sum12(
    const float* __restrict__ feat, const int* __restrict__ src,
    const int* __restrict__ head, const int* __restrict__ nxt,
    float* __restrict__ sums, float* __restrict__ cnt)
{
  const int lane = threadIdx.x & 63;
  const int w = blockIdx.x * (blockDim.x >> 6) + (threadIdx.x >> 6);
  const int nA = 2 * w;
  if (nA >= N_NODES) return;
  const int nB = nA + 1;
  const bool hasB = (nB < N_NODES);

  int eA0 = RFL(head[(size_t)0 * N_NODES + nA]);
  int eA1 = RFL(head[(size_t)1 * N_NODES + nA]);
  int eA2 = RFL(head[(size_t)2 * N_NODES + nA]);
  int eA3 = RFL(head[(size_t)3 * N_NODES + nA]);
  int eA4 = RFL(head[(size_t)4 * N_NODES + nA]);
  int eA5 = RFL(head[(size_t)5 * N_NODES + nA]);
  int eB0 = hasB ? RFL(head[(size_t)0 * N_NODES + nB]) : -1;
  int eB1 = hasB ? RFL(head[(size_t)1 * N_NODES + nB]) : -1;
  int eB2 = hasB ? RFL(head[(size_t)2 * N_NODES + nB]) : -1;
  int eB3 = hasB ? RFL(head[(size_t)3 * N_NODES + nB]) : -1;
  int eB4 = hasB ? RFL(head[(size_t)4 * N_NODES + nB]) : -1;
  int eB5 = hasB ? RFL(head[(size_t)5 * N_NODES + nB]) : -1;

  float vA0 = 0.f, vA1 = 0.f, vA2 = 0.f, vA3 = 0.f, vA4 = 0.f, vA5 = 0.f;
  float vB0 = 0.f, vB1 = 0.f, vB2 = 0.f, vB3 = 0.f, vB4 = 0.f, vB5 = 0.f;
  int cA0 = 0, cA1 = 0, cA2 = 0, cA3 = 0, cA4 = 0, cA5 = 0;
  int cB0 = 0, cB1 = 0, cB2 = 0, cB3 = 0, cB4 = 0, cB5 = 0;

  while ((eA0 >= 0) | (eA1 >= 0) | (eA2 >= 0) | (eA3 >= 0) | (eA4 >= 0) | (eA5 >= 0) |
         (eB0 >= 0) | (eB1 >= 0) | (eB2 >= 0) | (eB3 >= 0) | (eB4 >= 0) | (eB5 >= 0)) {
    const int aA0 = eA0 < 0 ? 0 : eA0, aA1 = eA1 < 0 ? 0 : eA1, aA2 = eA2 < 0 ? 0 : eA2;
    const int aA3 = eA3 < 0 ? 0 : eA3, aA4 = eA4 < 0 ? 0 : eA4, aA5 = eA5 < 0 ? 0 : eA5;
    const int aB0 = eB0 < 0 ? 0 : eB0, aB1 = eB1 < 0 ? 0 : eB1, aB2 = eB2 < 0 ? 0 : eB2;
    const int aB3 = eB3 < 0 ? 0 : eB3, aB4 = eB4 < 0 ? 0 : eB4, aB5 = eB5 < 0 ? 0 : eB5;

    const int sA0 = RFL(src[aA0]), sA1 = RFL(src[aA1]), sA2 = RFL(src[aA2]);
    const int sA3 = RFL(src[aA3]), sA4 = RFL(src[aA4]), sA5 = RFL(src[aA5]);
    const int sB0 = RFL(src[aB0]), sB1 = RFL(src[aB1]), sB2 = RFL(src[aB2]);
    const int sB3 = RFL(src[aB3]), sB4 = RFL(src[aB4]), sB5 = RFL(src[aB5]);
    const int xA0 = RFL(nxt[aA0]), xA1 = RFL(nxt[aA1]), xA2 = RFL(nxt[aA2]);
    const int xA3 = RFL(nxt[aA3]), xA4 = RFL(nxt[aA4]), xA5 = RFL(nxt[aA5]);
    const int xB0 = RFL(nxt[aB0]), xB1 = RFL(nxt[aB1]), xB2 = RFL(nxt[aB2]);
    const int xB3 = RFL(nxt[aB3]), xB4 = RFL(nxt[aB4]), xB5 = RFL(nxt[aB5]);

    const float fA0 = feat[(size_t)sA0 * FDIM + lane];
    const float fA1 = feat[(size_t)sA1 * FDIM + lane];
    const float fA2 = feat[(size_t)sA2 * FDIM + lane];
    const float fA3 = feat[(size_t)sA3 * FDIM + lane];
    const float fA4 = feat[(size_t)sA4 * FDIM + lane];
    const float fA5 = feat[(size_t)sA5 * FDIM + lane];
    const float fB0 = feat[(size_t)sB0 * FDIM + lane];
    const float fB1 = feat[(size_t)sB1 * FDIM + lane];
    const float fB2 = feat[(size_t)sB2 * FDIM + lane];
    const float fB3 = feat[(size_t)sB3 * FDIM + lane];
    const float fB4 = feat[(size_t)sB4 * FDIM + lane];
    const float fB5 = feat[(size_t)sB5 * FDIM + lane];

    vA0 += (eA0 >= 0) ? fA0 : 0.0f;  cA0 += (eA0 >= 0);  eA0 = (eA0 >= 0) ? xA0 : -1;
    vA1 += (eA1 >= 0) ? fA1 : 0.0f;  cA1 += (eA1 >= 0);  eA1 = (eA1 >= 0) ? xA1 : -1;
    vA2 += (eA2 >= 0) ? fA2 : 0.0f;  cA2 += (eA2 >= 0);  eA2 = (eA2 >= 0) ? xA2 : -1;
    vA3 += (eA3 >= 0) ? fA3 : 0.0f;  cA3 += (eA3 >= 0);  eA3 = (eA3 >= 0) ? xA3 : -1;
    vA4 += (eA4 >= 0) ? fA4 : 0.0f;  cA4 += (eA4 >= 0);  eA4 = (eA4 >= 0) ? xA4 : -1;
    vA5 += (eA5 >= 0) ? fA5 : 0.0f;  cA5 += (eA5 >= 0);  eA5 = (eA5 >= 0) ? xA5 : -1;
    vB0 += (eB0 >= 0) ? fB0 : 0.0f;  cB0 += (eB0 >= 0);  eB0 = (eB0 >= 0) ? xB0 : -1;
    vB1 += (eB1 >= 0) ? fB1 : 0.0f;  cB1 += (eB1 >= 0);  eB1 = (eB1 >= 0) ? xB1 : -1;
    vB2 += (eB2 >= 0) ? fB2 : 0.0f;  cB2 += (eB2 >= 0);  eB2 = (eB2 >= 0) ? xB2 : -1;
    vB3 += (eB3 >= 0) ? fB3 : 0.0f;  cB3 += (eB3 >= 0);  eB3 = (eB3 >= 0) ? xB3 : -1;
    vB4 += (eB4 >= 0) ? fB4 : 0.0f;  cB4 += (eB4 >= 0);  eB4 = (eB4 >= 0) ? xB4 : -1;
    vB5 += (eB5 >= 0) ? fB5 : 0.0f;  cB5 += (eB5 >= 0);  eB5 = (eB5 >= 0) ? xB5 : -1;
  }

  sums[((size_t)0 * N_NODES + nA) * FDIM + lane] = vA0;
  sums[((size_t)1 * N_NODES + nA) * FDIM + lane] = vA1;
  sums[((size_t)2 * N_NODES + nA) * FDIM + lane] = vA2;
  sums[((size_t)3 * N_NODES + nA) * FDIM + lane] = vA3;
  sums[((size_t)4 * N_NODES + nA) * FDIM + lane] = vA4;
  sums[((size_t)5 * N_NODES + nA) * FDIM + lane] = vA5;
  if (hasB) {
    sums[((size_t)0 * N_NODES + nB) * FDIM + lane] = vB0;
    sums[((size_t)1 * N_NODES + nB) * FDIM + lane] = vB1;
    sums[((size_t)2 * N_NODES + nB) * FDIM + lane] = vB2;
    sums[((size_t)3 * N_NODES + nB) * FDIM + lane] = vB3;
    sums[((size_t)4 * N_NODES + nB) * FDIM + lane] = vB4;
    sums[((size_t)5 * N_NODES + nB) * FDIM + lane] = vB5;
  }
  if (lane == 0) {
    cnt[(size_t)0 * N_NODES + nA] = (float)cA0;
    cnt[(size_t)1 * N_NODES + nA] = (float)cA1;
    cnt[(size_t)2 * N_NODES + nA] = (float)cA2;
    cnt[(size_t)3 * N_NODES + nA] = (float)cA3;
    cnt[(size_t)4 * N_NODES + nA] = (float)cA4;
    cnt[(size_t)5 * N_NODES + nA] = (float)cA5;
    if (hasB) {
      cnt[(size_t)0 * N_NODES + nB] = (float)cB0;
      cnt[(size_t)1 * N_NODES + nB] = (float)cB1;
      cnt[(size_t)2 * N_NODES + nB] = (float)cB2;
      cnt[(size_t)3 * N_NODES + nB] = (float)cB3;
      cnt[(size_t)4 * N_NODES + nB] = (float)cB4;
      cnt[(size_t)5 * N_NODES + nB] = (float)cB5;
    }
  }
}

// ===== VERBATIM r16 gemm (two-plane staging; proven win 147 -> ~95us) =====
template <int OUTF, int JBLK>
__global__ __launch_bounds__(256) void k_gemm_tile2(
    const float* __restrict__ sums, const float* __restrict__ cnt,
    const float* __restrict__ W, const float* __restrict__ bias,
    float* __restrict__ out)
{
  __shared__ float lds[2][64 * PADF];   // 2 planes x 17408 B
  const int tid = threadIdx.x;
  const int lane = tid & 63;
  const int n0 = blockIdx.x * 64;
  const int jb = __builtin_amdgcn_readfirstlane(tid >> 6) * JBLK;

  int n = n0 + lane;
  const bool valid = (n < N_NODES);
  if (!valid) n = N_NODES - 1;

  float acc[JBLK];
  #pragma unroll
  for (int j = 0; j < JBLK; ++j) acc[j] = bias[jb + j];

  #pragma unroll 1
  for (int tp = 0; tp < T_STEPS / 2; ++tp) {
    __syncthreads();   // previous pair fully consumed before overwrite
    // stage planes t=2tp, 2tp+1: 2048 items, 8 per thread, all loads first
    float4 reg[8];
    #pragma unroll
    for (int it = 0; it < 8; ++it) {
      const int item = tid + it * 256;
      const int q = item & 15;
      const int u = (item >> 4) & 63;
      const int pl = item >> 10;
      const int nn = n0 + u;
      reg[it] = make_float4(0.f, 0.f, 0.f, 0.f);
      if (nn < N_NODES)
        reg[it] = *(const float4*)(sums + ((size_t)(2 * tp + pl) * N_NODES + nn) * FDIM + q * 4);
    }
    #pragma unroll
    for (int it = 0; it < 8; ++it) {
      const int item = tid + it * 256;
      const int q = item & 15;
      const int u = (item >> 4) & 63;
      const int pl = item >> 10;
      *(float4*)(&lds[pl][u * PADF + q * 4]) = reg[it];
    }
    __syncthreads();

    #pragma unroll
    for (int pl = 0; pl < 2; ++pl) {
      const int t = 2 * tp + pl;

      // ---- pass A for this t (verbatim r1 rounding) ----
      const float c  = cnt[(size_t)t * N_NODES + n];
      const float rc = 1.0f / fmaxf(c, 1.0f);
      const float4* row = (const float4*)(&lds[pl][lane * PADF]);
      float ss = 0.0f;
      #pragma unroll
      for (int q = 0; q < FDIM / 4; ++q) {
        float4 v = row[q];
        float m0 = v.x * rc, m1 = v.y * rc, m2 = v.z * rc, m3 = v.w * rc;
        ss += m0 * m0 + m1 * m1 + m2 * m2 + m3 * m3;
      }
      const float norm = 1.0f - C2 * ss;
      const float s = rc / norm;

      // ---- pass B partial for this t, j-slice [jb, jb+JBLK) ----
      #pragma unroll
      for (int q8 = 0; q8 < FDIM / 8; ++q8) {
        const float4 a = row[q8 * 2 + 0];
        const float4 b4 = row[q8 * 2 + 1];
        const float hv[8] = {a.x, a.y, a.z, a.w, b4.x, b4.y, b4.z, b4.w};
        const float* wr = W + ((size_t)t * FDIM + q8 * 8) * OUTF + jb;
        #pragma unroll
        for (int i = 0; i < 8; ++i) {
          const float hs = hv[i] * s;
          #pragma unroll
          for (int j = 0; j < JBLK; ++j)
            acc[j] = fmaf(hs, wr[i * OUTF + j], acc[j]);
        }
      }
    }
  }

  if (valid) {
    float* o = out + (size_t)n * OUTF + jb;
    #pragma unroll
    for (int j = 0; j < JBLK; ++j) o[j] = fmaxf(acc[j], 0.0f);
  }
}

extern "C" void kernel_launch(void* const* d_in, const int* in_sizes, int n_in,
                              void* d_out, int out_size, void* d_ws, size_t ws_size,
                              hipStream_t stream) {
  const float* x  = (const float*)d_in[0];
  const int*  ei  = (const int*)d_in[1];
  const int*  tix = (const int*)d_in[2];
  const float* W1 = (const float*)d_in[3];
  const float* b1 = (const float*)d_in[4];
  const float* W2 = (const float*)d_in[5];
  const float* b2 = (const float*)d_in[6];

  const int* src = ei;
  const int* dst = ei + N_EDGES;

  // Workspace: head[SEG] | nxt[NE] | sums[SEG*64] | cnt[SEG] | h1[NN*64]
  int*   head = (int*)d_ws;
  int*   nxt  = head + SEG;
  float* sums = (float*)(nxt + N_EDGES);
  float* cnt  = sums + (size_t)SEG * FDIM;
  float* h1   = cnt + SEG;

  const int nwaves   = (N_NODES + 1) / 2;        // 2 nodes per wave
  const int sum_grid = (nwaves + 3) / 4;         // 4 waves/block
  const int ngrp     = (N_NODES + 63) / 64;      // 1563 64-node groups

  hipMemsetAsync(head, 0xFF, (size_t)SEG * sizeof(int), stream);
  k_build<<<(N_EDGES + 255) / 256, 256, 0, stream>>>(dst, tix, head, nxt);

  // Layer 1
  k_sum12<<<sum_grid, 256, 0, stream>>>(x, src, head, nxt, sums, cnt);
  k_gemm_tile2<64, 16><<<ngrp, 256, 0, stream>>>(sums, cnt, W1, b1, h1);

  // Layer 2 (same edge lists; cnt identical but rewritten -- harmless)
  k_sum12<<<sum_grid, 256, 0, stream>>>(h1, src, head, nxt, sums, cnt);
  k_gemm_tile2<16, 4><<<ngrp, 256, 0, stream>>>(sums, cnt, W2, b2, (float*)d_out);
}